// Round 1
// baseline (195.384 us; speedup 1.0000x reference)
//
#include <hip/hip_runtime.h>

// Problem constants (from reference):
//   input [2, 2048, 512] fp32, Wq/Wk/Wv [512,4096], Wo [4096,512], biases fp32.
// Reference quirk: final einsum 'nhkq,nvhd->nvhd' sums the softmax weights over
// BOTH sequence axes -> scalar per (n,h) == SEQ exactly (softmax rows sum to 1).
// So out = SEQ*(input@Wv + bv) @ Wo + bo. Q, K, mask, softmax are dead code.
// We fuse further: Wc = SEQ*(Wv@Wo) [512x512], cvec = SEQ*(bv@Wo); then
// out = input @ Wc + cvec + bo.  Total ~4.3 GFLOP fp32.

#define DM   512      // d_model
#define HC   4096     // concat width
#define SEQF 2048.0f  // seq len (the softmax-weight sum per (n,h))
#define MROWS 4096    // BATCH*SEQ

// ---------------- Kernel A: Wc[i][n] += SEQ * sum_j Wv[i][j]*Wo[j][n] --------
// grid (8 n-tiles, 8 i-tiles, 8 k-chunks), 256 threads, 64x64 tile, 4x4/thread.
__global__ __launch_bounds__(256) void gemm_wc(const float* __restrict__ Wv,
                                               const float* __restrict__ Wo,
                                               float* __restrict__ Wc) {
    __shared__ float As[32][68];  // [j][i] (transposed A tile), +4 pad
    __shared__ float Bs[32][68];  // [j][n]
    const int tid = threadIdx.x;
    const int tx = tid & 15, ty = tid >> 4;
    const int i0 = blockIdx.y * 64;
    const int n0 = blockIdx.x * 64;
    const int jbase = blockIdx.z * 512;

    float acc[4][4] = {};
    for (int js = 0; js < 512; js += 32) {
        const int j0 = jbase + js;
        // A tile: Wv[i0..+63][j0..+31] -> As[j][i]
#pragma unroll
        for (int rep = 0; rep < 2; ++rep) {
            const int flat = tid + rep * 256;     // 0..511
            const int row  = flat >> 3;           // 0..63 (i)
            const int col4 = flat & 7;            // 0..7  (j/4)
            const float4 v = *reinterpret_cast<const float4*>(
                &Wv[(size_t)(i0 + row) * HC + j0 + col4 * 4]);
            As[col4 * 4 + 0][row] = v.x;
            As[col4 * 4 + 1][row] = v.y;
            As[col4 * 4 + 2][row] = v.z;
            As[col4 * 4 + 3][row] = v.w;
        }
        // B tile: Wo[j0..+31][n0..+63] -> Bs[j][n]
#pragma unroll
        for (int rep = 0; rep < 2; ++rep) {
            const int flat = tid + rep * 256;
            const int row  = flat >> 4;           // 0..31 (j)
            const int col4 = flat & 15;           // 0..15 (n/4)
            const float4 v = *reinterpret_cast<const float4*>(
                &Wo[(size_t)(j0 + row) * DM + n0 + col4 * 4]);
            *reinterpret_cast<float4*>(&Bs[row][col4 * 4]) = v;
        }
        __syncthreads();
#pragma unroll
        for (int kk = 0; kk < 32; ++kk) {
            const float4 a = *reinterpret_cast<const float4*>(&As[kk][ty * 4]);
            const float4 b = *reinterpret_cast<const float4*>(&Bs[kk][tx * 4]);
            const float av[4] = {a.x, a.y, a.z, a.w};
            const float bw[4] = {b.x, b.y, b.z, b.w};
#pragma unroll
            for (int r = 0; r < 4; ++r)
#pragma unroll
                for (int c = 0; c < 4; ++c)
                    acc[r][c] = fmaf(av[r], bw[c], acc[r][c]);
        }
        __syncthreads();
    }
#pragma unroll
    for (int r = 0; r < 4; ++r)
#pragma unroll
        for (int c = 0; c < 4; ++c)
            atomicAdd(&Wc[(size_t)(i0 + ty * 4 + r) * DM + n0 + tx * 4 + c],
                      SEQF * acc[r][c]);
}

// ---------------- Bias: cvec[n] += SEQ * sum_j bv[j]*Wo[j][n] ----------------
__global__ __launch_bounds__(512) void bias_c(const float* __restrict__ bv,
                                              const float* __restrict__ Wo,
                                              float* __restrict__ cvec) {
    const int n  = threadIdx.x;         // 0..511
    const int j0 = blockIdx.x * 128;    // 32 blocks cover j=0..4095
    float s = 0.f;
    for (int j = j0; j < j0 + 128; ++j)
        s = fmaf(bv[j], Wo[(size_t)j * DM + n], s);
    atomicAdd(&cvec[n], SEQF * s);
}

// ---------------- Kernel B: out[m][n] = sum_k X[m][k]*Wc[k][n] + cvec[n]+bo[n]
// grid (8 n-tiles, 64 m-tiles), 256 threads, 64x64 tile, 4x4/thread, K=512.
__global__ __launch_bounds__(256) void gemm_out(const float* __restrict__ X,
                                                const float* __restrict__ Wc,
                                                const float* __restrict__ cvec,
                                                const float* __restrict__ bo,
                                                float* __restrict__ out) {
    __shared__ float As[32][68];  // [k][m]
    __shared__ float Bs[32][68];  // [k][n]
    const int tid = threadIdx.x;
    const int tx = tid & 15, ty = tid >> 4;
    const int m0 = blockIdx.y * 64;
    const int n0 = blockIdx.x * 64;

    float acc[4][4] = {};
    for (int k0 = 0; k0 < DM; k0 += 32) {
        // A tile: X[m0..+63][k0..+31] -> As[k][m]
#pragma unroll
        for (int rep = 0; rep < 2; ++rep) {
            const int flat = tid + rep * 256;
            const int row  = flat >> 3;           // 0..63 (m)
            const int col4 = flat & 7;            // 0..7  (k/4)
            const float4 v = *reinterpret_cast<const float4*>(
                &X[(size_t)(m0 + row) * DM + k0 + col4 * 4]);
            As[col4 * 4 + 0][row] = v.x;
            As[col4 * 4 + 1][row] = v.y;
            As[col4 * 4 + 2][row] = v.z;
            As[col4 * 4 + 3][row] = v.w;
        }
        // B tile: Wc[k0..+31][n0..+63] -> Bs[k][n]
#pragma unroll
        for (int rep = 0; rep < 2; ++rep) {
            const int flat = tid + rep * 256;
            const int row  = flat >> 4;           // 0..31 (k)
            const int col4 = flat & 15;           // 0..15 (n/4)
            const float4 v = *reinterpret_cast<const float4*>(
                &Wc[(size_t)(k0 + row) * DM + n0 + col4 * 4]);
            *reinterpret_cast<float4*>(&Bs[row][col4 * 4]) = v;
        }
        __syncthreads();
#pragma unroll
        for (int kk = 0; kk < 32; ++kk) {
            const float4 a = *reinterpret_cast<const float4*>(&As[kk][ty * 4]);
            const float4 b = *reinterpret_cast<const float4*>(&Bs[kk][tx * 4]);
            const float av[4] = {a.x, a.y, a.z, a.w};
            const float bw[4] = {b.x, b.y, b.z, b.w};
#pragma unroll
            for (int r = 0; r < 4; ++r)
#pragma unroll
                for (int c = 0; c < 4; ++c)
                    acc[r][c] = fmaf(av[r], bw[c], acc[r][c]);
        }
        __syncthreads();
    }
#pragma unroll
    for (int r = 0; r < 4; ++r) {
        const int m = m0 + ty * 4 + r;
#pragma unroll
        for (int c = 0; c < 4; ++c) {
            const int n = n0 + tx * 4 + c;
            out[(size_t)m * DM + n] = acc[r][c] + cvec[n] + bo[n];
        }
    }
}

extern "C" void kernel_launch(void* const* d_in, const int* in_sizes, int n_in,
                              void* d_out, int out_size, void* d_ws, size_t ws_size,
                              hipStream_t stream) {
    // setup_inputs order: 0 input, 1 mask, 2 Wq, 3 bq, 4 Wk, 5 bk,
    //                     6 Wv, 7 bv, 8 Wo, 9 bo.  (mask/Wq/bq/Wk/bk unused)
    const float* input = (const float*)d_in[0];
    const float* Wv    = (const float*)d_in[6];
    const float* bv    = (const float*)d_in[7];
    const float* Wo    = (const float*)d_in[8];
    const float* bo    = (const float*)d_in[9];
    float* out = (float*)d_out;

    float* Wc   = (float*)d_ws;            // 512*512 floats
    float* cvec = Wc + DM * DM;            // 512 floats
    hipMemsetAsync(d_ws, 0, (size_t)(DM * DM + DM) * sizeof(float), stream);

    dim3 gA(8, 8, 8);                       // n-tiles, i-tiles, k-chunks
    gemm_wc<<<gA, 256, 0, stream>>>(Wv, Wo, Wc);
    bias_c<<<32, 512, 0, stream>>>(bv, Wo, cvec);
    dim3 gB(8, MROWS / 64);                 // n-tiles, m-tiles
    gemm_out<<<gB, 256, 0, stream>>>(input, Wc, cvec, bo, out);
}